// Round 12
// baseline (187.445 us; speedup 1.0000x reference)
//
#include <hip/hip_runtime.h>
#include <hip/hip_bf16.h>

constexpr int N = 50000;
constexpr int E = 800000;
constexpr int D = 64;
constexpr int GSZ = N / 8;        // 6250 nodes per XCD group
constexpr int SLOTS = 64;         // fixed CSR row width (max deg ~40 whp)
constexpr int ZB = 49;            // zero blocks: 12500 int4 / 256
constexpr int PB = 1563;          // prepx blocks: 400000 uint4-groups / 256
constexpr int EBLK = E / 256;     // 3125
constexpr int LSTR = 36;          // LDS aax row stride in uints (bank-spread, 16B-aligned)

typedef __attribute__((ext_vector_type(8))) short s8v;    // 8 bf16
typedef __attribute__((ext_vector_type(4))) float f32x4;  // mfma accumulator

struct BranchParams {
  const float* W[5];
  const float* b[5];
  const float* wa[5];
  const float* ba[5];
};

__device__ __forceinline__ short f2bf(float f) {  // RNE float->bf16 bits
  unsigned u = __float_as_uint(f);
  u += 0x7fff + ((u >> 16) & 1);
  return (short)(u >> 16);
}
__device__ __forceinline__ float bflo(unsigned v) { return __uint_as_float(v << 16); }
__device__ __forceinline__ float bfhi(unsigned v) { return __uint_as_float(v & 0xffff0000u); }
__device__ __forceinline__ float bfs(short s) {
  return __uint_as_float(((unsigned)(unsigned short)s) << 16);
}
__device__ __forceinline__ unsigned pack2(float lo, float hi) {
  return ((unsigned)(unsigned short)f2bf(lo)) |
         (((unsigned)(unsigned short)f2bf(hi)) << 16);
}

__device__ __forceinline__ void prepw_frag(const BranchParams& P,
                                           short* __restrict__ wf,
                                           int bfrag, int lane) {
  int br = bfrag >> 3, ct = (bfrag >> 1) & 3, kk = bfrag & 1;
  const float* W = P.W[br];
  int col = ct * 16 + (lane & 15);
  int k0 = kk * 32 + (lane >> 4) * 8;
  s8v v;
#pragma unroll
  for (int j = 0; j < 8; ++j) v[j] = f2bf(W[(k0 + j) * D + col]);
  ((s8v*)wf)[bfrag * 64 + lane] = v;
}

// ---- K1: zero slot-cursors ----------------------------------------------
__global__ __launch_bounds__(256) void k_zero(int4* __restrict__ pos4) {
  int t = blockIdx.x * 256 + threadIdx.x;
  if (t < N / 4) pos4[t] = int4{0, 0, 0, 0};
}

// ---- K2: W-frags | x->bf16 | fixed-slot XCD-partitioned CSR fill --------
__global__ __launch_bounds__(256) void k_fill_prep(
    const int* __restrict__ ei, int* __restrict__ pos,
    ushort* __restrict__ srcs, const float* __restrict__ x,
    uint* __restrict__ xbf, BranchParams P, short* __restrict__ wf) {
  int b = blockIdx.x;
  if (b == 0) {
    int wid = threadIdx.x >> 6, lane = threadIdx.x & 63;
    for (int bfrag = wid; bfrag < 40; bfrag += 4) prepw_frag(P, wf, bfrag, lane);
  } else if (b <= PB) {
    int t = (b - 1) * 256 + threadIdx.x;
    if (t < N * D / 8) {
      const float4* p = (const float4*)(x + (size_t)t * 8);
      float4 a = p[0], c = p[1];
      uint4 o;
      o.x = pack2(a.x, a.y);
      o.y = pack2(a.z, a.w);
      o.z = pack2(c.x, c.y);
      o.w = pack2(c.z, c.w);
      ((uint4*)xbf)[t] = o;
    }
  } else {
    int fb = b - 1 - PB;                 // 0 .. 8*EBLK-1
    int g = fb & 7;
    int e = (fb >> 3) * 256 + threadIdx.x;
    int dst = ei[E + e];
    if ((unsigned)(dst - g * GSZ) < (unsigned)GSZ) {
      int slot = atomicAdd(&pos[dst], 1);
      if (slot < SLOTS) srcs[dst * SLOTS + slot] = (ushort)ei[e];
    }
  }
}

// ---- shared agg body: mean over fixed-slot CSR row (one node, one wave) --
// returns packed bf16 pair for this lane's feature pair (valid on half==0).
__device__ __forceinline__ uint agg_row(
    const int* __restrict__ pos, const ushort* __restrict__ srcs,
    const uint* __restrict__ inbf, int node, int lane) {
  int half = lane >> 5;
  int fp = lane & 31;
  int deg = pos[node];
  int m = min(deg, SLOTS);
  int start = node * SLOTS;
  int end = start + m;
  int np = m >> 1;
  float sx0 = 0.f, sy0 = 0.f, sx1 = 0.f, sy1 = 0.f;
  float sx2 = 0.f, sy2 = 0.f, sx3 = 0.f, sy3 = 0.f;
  int e = start + half;
  int i = 0;
  for (; i + 4 <= np; i += 4, e += 8) {  // 8 row-gathers in flight per wave
    int s0 = srcs[e], s1 = srcs[e + 2], s2 = srcs[e + 4], s3 = srcs[e + 6];
    uint v0 = inbf[s0 * 32 + fp];
    uint v1 = inbf[s1 * 32 + fp];
    uint v2 = inbf[s2 * 32 + fp];
    uint v3 = inbf[s3 * 32 + fp];
    sx0 += bflo(v0); sy0 += bfhi(v0);
    sx1 += bflo(v1); sy1 += bfhi(v1);
    sx2 += bflo(v2); sy2 += bfhi(v2);
    sx3 += bflo(v3); sy3 += bfhi(v3);
  }
  for (; i < np; ++i, e += 2) {
    int s0 = srcs[e];
    uint v0 = inbf[s0 * 32 + fp];
    sx0 += bflo(v0); sy0 += bfhi(v0);
  }
  if ((m & 1) && half == 0) {  // odd tail: half 0 only
    int s0 = srcs[end - 1];
    uint v0 = inbf[s0 * 32 + fp];
    sx0 += bflo(v0); sy0 += bfhi(v0);
  }
  float sx = (sx0 + sx1) + (sx2 + sx3);
  float sy = (sy0 + sy1) + (sy2 + sy3);
  sx += __shfl_xor(sx, 32);
  sy += __shfl_xor(sy, 32);
  float inv = 1.0f / fmaxf((float)deg, 1.0f);
  return pack2(sx * inv, sy * inv);
}

// ---- K3: mean aggregation x -> ax (global out) --------------------------
__global__ __launch_bounds__(256) void k_agg(
    const int* __restrict__ pos, const ushort* __restrict__ srcs,
    const uint* __restrict__ inbf, uint* __restrict__ outbf) {
  int node = blockIdx.x * 4 + (threadIdx.x >> 6);
  int lane = threadIdx.x & 63;
  uint r = agg_row(pos, srcs, inbf, node, lane);
  if ((lane >> 5) == 0) outbf[node * 32 + (lane & 31)] = r;
}

// ---- K4: agg ax->aax (16 waves, 1 node/wave, LDS) + fused MFMA branch ---
__global__ __launch_bounds__(1024, 4) void k_agg2_branch(
    const int* __restrict__ pos, const ushort* __restrict__ srcs,
    const uint* __restrict__ axbf, const ushort* __restrict__ xbf,
    BranchParams P, const short* __restrict__ wf, float* __restrict__ out) {
  __shared__ uint aaxl[16 * LSTR];
  const int lane = threadIdx.x & 63;
  const int wid = threadIdx.x >> 6;   // 0..15 — one node per wave
  const int base = blockIdx.x * 16;   // N/16 = 3125 blocks exactly

  // agg phase: full TLP — each of the 16 waves computes one aax row
  {
    uint r = agg_row(pos, srcs, axbf, base + wid, lane);
    if ((lane >> 5) == 0) aaxl[wid * LSTR + (lane & 31)] = r;
  }
  __syncthreads();
  if (wid != 0) return;

  // branch phase (wave 0): MFMA over x, ax (global bf16) and aax (LDS)
  const int l16 = lane & 15;
  const int kg = lane >> 4;

  const s8v* xr = (const s8v*)(xbf + (size_t)(base + l16) * D);
  const s8v* ar = (const s8v*)((const ushort*)axbf + (size_t)(base + l16) * D);
  const s8v* cr = (const s8v*)(aaxl + l16 * LSTR);
  s8v xv[2], av[2], bv[2];
  xv[0] = xr[kg]; xv[1] = xr[4 + kg];
  av[0] = ar[kg]; av[1] = ar[4 + kg];
  bv[0] = cr[kg]; bv[1] = cr[4 + kg];

  s8v hpv[2], hp2v[2];
#pragma unroll
  for (int kk = 0; kk < 2; ++kk) {
#pragma unroll
    for (int j = 0; j < 8; ++j) {
      float fx = bfs(xv[kk][j]), fa = bfs(av[kk][j]), fb = bfs(bv[kk][j]);
      hpv[kk][j] = f2bf(fx - fa);
      hp2v[kk][j] = f2bf(fx - 2.0f * fa + fb);
    }
  }

  f32x4 oacc[4] = {{0.f, 0.f, 0.f, 0.f}, {0.f, 0.f, 0.f, 0.f},
                   {0.f, 0.f, 0.f, 0.f}, {0.f, 0.f, 0.f, 0.f}};
  const s8v* wf8 = (const s8v*)wf;

#pragma unroll
  for (int brn = 0; brn < 5; ++brn) {
    s8v a0, a1;
    switch (brn) {
      case 0: a0 = hpv[0]; a1 = hpv[1]; break;
      case 1: a0 = av[0]; a1 = av[1]; break;
      case 2: a0 = xv[0]; a1 = xv[1]; break;
      case 3: a0 = hp2v[0]; a1 = hp2v[1]; break;
      default: a0 = bv[0]; a1 = bv[1]; break;
    }
    f32x4 acc[4];
#pragma unroll
    for (int ct = 0; ct < 4; ++ct) {
      f32x4 a = {0.f, 0.f, 0.f, 0.f};
      a = __builtin_amdgcn_mfma_f32_16x16x32_bf16(
          a0, wf8[((brn * 4 + ct) * 2 + 0) * 64 + lane], a, 0, 0, 0);
      a = __builtin_amdgcn_mfma_f32_16x16x32_bf16(
          a1, wf8[((brn * 4 + ct) * 2 + 1) * 64 + lane], a, 0, 0, 0);
      acc[ct] = a;
    }
    float bcol[4], wacol[4];
#pragma unroll
    for (int ct = 0; ct < 4; ++ct) {
      bcol[ct] = P.b[brn][ct * 16 + l16];
      wacol[ct] = P.wa[brn][ct * 16 + l16];
    }
    const float bav = P.ba[brn][0];
    // C/D layout: col = lane&15 (+16*ct), row = kg*4 + i
#pragma unroll
    for (int i = 0; i < 4; ++i) {
      float h[4], gg = 0.f;
#pragma unroll
      for (int ct = 0; ct < 4; ++ct) {
        h[ct] = fmaxf(acc[ct][i] + bcol[ct], 0.f);
        gg = fmaf(h[ct], wacol[ct], gg);
      }
#pragma unroll
      for (int o = 1; o < 16; o <<= 1) gg += __shfl_xor(gg, o);
      float alpha = 1.0f / (1.0f + __expf(-(gg + bav)));
#pragma unroll
      for (int ct = 0; ct < 4; ++ct) oacc[ct][i] = fmaf(alpha, h[ct], oacc[ct][i]);
    }
  }
#pragma unroll
  for (int ct = 0; ct < 4; ++ct)
#pragma unroll
    for (int i = 0; i < 4; ++i)
      out[(size_t)(base + kg * 4 + i) * D + ct * 16 + l16] = oacc[ct][i];
}

extern "C" void kernel_launch(void* const* d_in, const int* in_sizes, int n_in,
                              void* d_out, int out_size, void* d_ws, size_t ws_size,
                              hipStream_t stream) {
  const float* x = (const float*)d_in[0];
  const int* ei = (const int*)d_in[1];
  BranchParams P;
  for (int i = 0; i < 5; ++i) {
    P.W[i] = (const float*)d_in[2 + 4 * i];
    P.b[i] = (const float*)d_in[3 + 4 * i];
    P.wa[i] = (const float*)d_in[4 + 4 * i];
    P.ba[i] = (const float*)d_in[5 + 4 * i];
  }

  // workspace: xbf 6.4M | axbf 6.4M | pos 200K | srcs 6.4M | wf 40K
  char* w = (char*)d_ws;
  uint* xbf = (uint*)w;      w += (size_t)N * D * 2;
  uint* axbf = (uint*)w;     w += (size_t)N * D * 2;
  int* pos = (int*)w;        w += (size_t)N * 4;
  ushort* srcs = (ushort*)w; w += (size_t)N * SLOTS * 2;
  short* wf = (short*)w;

  hipLaunchKernelGGL(k_zero, dim3(ZB), dim3(256), 0, stream, (int4*)pos);
  hipLaunchKernelGGL(k_fill_prep, dim3(1 + PB + 8 * EBLK), dim3(256), 0, stream,
                     ei, pos, srcs, x, xbf, P, wf);
  hipLaunchKernelGGL(k_agg, dim3(N / 4), dim3(256), 0, stream, pos, srcs, xbf, axbf);
  hipLaunchKernelGGL(k_agg2_branch, dim3(N / 16), dim3(1024), 0, stream,
                     pos, srcs, axbf, (const ushort*)xbf, P, wf, (float*)d_out);
}

// Round 13
// 114.214 us; speedup vs baseline: 1.6412x; 1.6412x over previous
//
#include <hip/hip_runtime.h>
#include <hip/hip_bf16.h>

constexpr int N = 50000;
constexpr int E = 800000;
constexpr int D = 64;
constexpr int GSZ = N / 8;        // 6250 nodes per XCD group
constexpr int SLOTS = 64;         // fixed CSR row width (max deg ~40 whp)
constexpr int ZB = 49;            // zero blocks: 12500 int4 / 256
constexpr int PB = 1563;          // prepx blocks: 400000 uint4-groups / 256
constexpr int EBLK = E / 256;     // 3125

typedef __attribute__((ext_vector_type(8))) short s8v;    // 8 bf16
typedef __attribute__((ext_vector_type(4))) float f32x4;  // mfma accumulator

struct BranchParams {
  const float* W[5];
  const float* b[5];
  const float* wa[5];
  const float* ba[5];
};

__device__ __forceinline__ short f2bf(float f) {  // RNE float->bf16 bits
  unsigned u = __float_as_uint(f);
  u += 0x7fff + ((u >> 16) & 1);
  return (short)(u >> 16);
}
__device__ __forceinline__ float bflo(unsigned v) { return __uint_as_float(v << 16); }
__device__ __forceinline__ float bfhi(unsigned v) { return __uint_as_float(v & 0xffff0000u); }
__device__ __forceinline__ float bfs(short s) {
  return __uint_as_float(((unsigned)(unsigned short)s) << 16);
}
__device__ __forceinline__ unsigned pack2(float lo, float hi) {
  return ((unsigned)(unsigned short)f2bf(lo)) |
         (((unsigned)(unsigned short)f2bf(hi)) << 16);
}

__device__ __forceinline__ void prepw_frag(const BranchParams& P,
                                           short* __restrict__ wf,
                                           int bfrag, int lane) {
  int br = bfrag >> 3, ct = (bfrag >> 1) & 3, kk = bfrag & 1;
  const float* W = P.W[br];
  int col = ct * 16 + (lane & 15);
  int k0 = kk * 32 + (lane >> 4) * 8;
  s8v v;
#pragma unroll
  for (int j = 0; j < 8; ++j) v[j] = f2bf(W[(k0 + j) * D + col]);
  ((s8v*)wf)[bfrag * 64 + lane] = v;
}

// ---- K1: zero slot-cursors | x->bf16 | W->frags (disjoint block ranges) --
__global__ __launch_bounds__(256) void k_zero_prep(
    int* __restrict__ pos, const float* __restrict__ x,
    uint* __restrict__ xbf, BranchParams P, short* __restrict__ wf) {
  int b = blockIdx.x;
  if (b < ZB) {
    int t = b * 256 + threadIdx.x;
    if (t < N / 4) ((int4*)pos)[t] = int4{0, 0, 0, 0};
  } else if (b < ZB + PB) {
    int t = (b - ZB) * 256 + threadIdx.x;
    if (t < N * D / 8) {
      const float4* p = (const float4*)(x + (size_t)t * 8);
      float4 a = p[0], c = p[1];
      uint4 o;
      o.x = pack2(a.x, a.y);
      o.y = pack2(a.z, a.w);
      o.z = pack2(c.x, c.y);
      o.w = pack2(c.z, c.w);
      ((uint4*)xbf)[t] = o;
    }
  } else {
    int wid = threadIdx.x >> 6, lane = threadIdx.x & 63;
    for (int bfrag = wid; bfrag < 40; bfrag += 4) prepw_frag(P, wf, bfrag, lane);
  }
}

// ---- K2: fixed-slot CSR fill, XCD-partitioned (8 replicas) --------------
// srcs[dst*64 + slot] = src ; pos[dst] ends up = true degree.
__global__ __launch_bounds__(256) void k_fill8(const int* __restrict__ ei,
                                               int* __restrict__ pos,
                                               ushort* __restrict__ srcs) {
  int g = blockIdx.x & 7;
  int e = (blockIdx.x >> 3) * 256 + threadIdx.x;
  int dst = ei[E + e];
  if ((unsigned)(dst - g * GSZ) < (unsigned)GSZ) {
    int slot = atomicAdd(&pos[dst], 1);
    if (slot < SLOTS) srcs[dst * SLOTS + slot] = (ushort)ei[e];
  }
}

// ---- K3/K4: mean aggregation (fixed-slot gather, 16 rows in flight) -----
__global__ __launch_bounds__(256) void k_agg(
    const int* __restrict__ pos, const ushort* __restrict__ srcs,
    const uint* __restrict__ inbf, uint* __restrict__ outbf) {
  int node = blockIdx.x * 4 + (threadIdx.x >> 6);
  int lane = threadIdx.x & 63;
  int half = lane >> 5;  // edge parity handled by this half-wave
  int fp = lane & 31;    // feature-pair index
  int deg = pos[node];
  int m = min(deg, SLOTS);
  int start = node * SLOTS;
  int end = start + m;
  int np = m >> 1;
  float sx0 = 0.f, sy0 = 0.f, sx1 = 0.f, sy1 = 0.f;
  float sx2 = 0.f, sy2 = 0.f, sx3 = 0.f, sy3 = 0.f;
  float sx4 = 0.f, sy4 = 0.f, sx5 = 0.f, sy5 = 0.f;
  float sx6 = 0.f, sy6 = 0.f, sx7 = 0.f, sy7 = 0.f;
  int e = start + half;
  int i = 0;
  for (; i + 8 <= np; i += 8, e += 16) {  // 16 row-gathers in flight per wave
    int s0 = srcs[e], s1 = srcs[e + 2], s2 = srcs[e + 4], s3 = srcs[e + 6];
    int s4 = srcs[e + 8], s5 = srcs[e + 10], s6 = srcs[e + 12], s7 = srcs[e + 14];
    uint v0 = inbf[s0 * 32 + fp];
    uint v1 = inbf[s1 * 32 + fp];
    uint v2 = inbf[s2 * 32 + fp];
    uint v3 = inbf[s3 * 32 + fp];
    uint v4 = inbf[s4 * 32 + fp];
    uint v5 = inbf[s5 * 32 + fp];
    uint v6 = inbf[s6 * 32 + fp];
    uint v7 = inbf[s7 * 32 + fp];
    sx0 += bflo(v0); sy0 += bfhi(v0);
    sx1 += bflo(v1); sy1 += bfhi(v1);
    sx2 += bflo(v2); sy2 += bfhi(v2);
    sx3 += bflo(v3); sy3 += bfhi(v3);
    sx4 += bflo(v4); sy4 += bfhi(v4);
    sx5 += bflo(v5); sy5 += bfhi(v5);
    sx6 += bflo(v6); sy6 += bfhi(v6);
    sx7 += bflo(v7); sy7 += bfhi(v7);
  }
  for (; i + 4 <= np; i += 4, e += 8) {   // 8 in flight
    int s0 = srcs[e], s1 = srcs[e + 2], s2 = srcs[e + 4], s3 = srcs[e + 6];
    uint v0 = inbf[s0 * 32 + fp];
    uint v1 = inbf[s1 * 32 + fp];
    uint v2 = inbf[s2 * 32 + fp];
    uint v3 = inbf[s3 * 32 + fp];
    sx0 += bflo(v0); sy0 += bfhi(v0);
    sx1 += bflo(v1); sy1 += bfhi(v1);
    sx2 += bflo(v2); sy2 += bfhi(v2);
    sx3 += bflo(v3); sy3 += bfhi(v3);
  }
  for (; i < np; ++i, e += 2) {
    int s0 = srcs[e];
    uint v0 = inbf[s0 * 32 + fp];
    sx0 += bflo(v0); sy0 += bfhi(v0);
  }
  if ((m & 1) && half == 0) {  // odd tail: half 0 only
    int s0 = srcs[end - 1];
    uint v0 = inbf[s0 * 32 + fp];
    sx0 += bflo(v0); sy0 += bfhi(v0);
  }
  float sx = ((sx0 + sx1) + (sx2 + sx3)) + ((sx4 + sx5) + (sx6 + sx7));
  float sy = ((sy0 + sy1) + (sy2 + sy3)) + ((sy4 + sy5) + (sy6 + sy7));
  sx += __shfl_xor(sx, 32);
  sy += __shfl_xor(sy, 32);
  if (half == 0) {
    float inv = 1.0f / fmaxf((float)deg, 1.0f);  // true degree denominator
    outbf[node * 32 + fp] = pack2(sx * inv, sy * inv);
  }
}

// ---- K5: fused 5-branch MFMA GEMM + ReLU + sigmoid gate + gated sum -----
__device__ __forceinline__ void branch_wave(
    const ushort* __restrict__ xbf, const ushort* __restrict__ axbf,
    const ushort* __restrict__ aaxbf, const BranchParams& P,
    const short* __restrict__ wf, float* __restrict__ out,
    int base, int lane) {
  const int l16 = lane & 15;
  const int kg = lane >> 4;

  const s8v* xr = (const s8v*)(xbf + (size_t)(base + l16) * D);
  const s8v* ar = (const s8v*)(axbf + (size_t)(base + l16) * D);
  const s8v* cr = (const s8v*)(aaxbf + (size_t)(base + l16) * D);
  s8v xv[2], av[2], bv[2];
  xv[0] = xr[kg]; xv[1] = xr[4 + kg];
  av[0] = ar[kg]; av[1] = ar[4 + kg];
  bv[0] = cr[kg]; bv[1] = cr[4 + kg];

  s8v hpv[2], hp2v[2];
#pragma unroll
  for (int kk = 0; kk < 2; ++kk) {
#pragma unroll
    for (int j = 0; j < 8; ++j) {
      float fx = bfs(xv[kk][j]), fa = bfs(av[kk][j]), fb = bfs(bv[kk][j]);
      hpv[kk][j] = f2bf(fx - fa);
      hp2v[kk][j] = f2bf(fx - 2.0f * fa + fb);
    }
  }

  f32x4 oacc[4] = {{0.f, 0.f, 0.f, 0.f}, {0.f, 0.f, 0.f, 0.f},
                   {0.f, 0.f, 0.f, 0.f}, {0.f, 0.f, 0.f, 0.f}};
  const s8v* wf8 = (const s8v*)wf;

#pragma unroll
  for (int brn = 0; brn < 5; ++brn) {
    s8v a0, a1;
    switch (brn) {
      case 0: a0 = hpv[0]; a1 = hpv[1]; break;
      case 1: a0 = av[0]; a1 = av[1]; break;
      case 2: a0 = xv[0]; a1 = xv[1]; break;
      case 3: a0 = hp2v[0]; a1 = hp2v[1]; break;
      default: a0 = bv[0]; a1 = bv[1]; break;
    }
    f32x4 acc[4];
#pragma unroll
    for (int ct = 0; ct < 4; ++ct) {
      f32x4 a = {0.f, 0.f, 0.f, 0.f};
      a = __builtin_amdgcn_mfma_f32_16x16x32_bf16(
          a0, wf8[((brn * 4 + ct) * 2 + 0) * 64 + lane], a, 0, 0, 0);
      a = __builtin_amdgcn_mfma_f32_16x16x32_bf16(
          a1, wf8[((brn * 4 + ct) * 2 + 1) * 64 + lane], a, 0, 0, 0);
      acc[ct] = a;
    }
    float bcol[4], wacol[4];
#pragma unroll
    for (int ct = 0; ct < 4; ++ct) {
      bcol[ct] = P.b[brn][ct * 16 + l16];
      wacol[ct] = P.wa[brn][ct * 16 + l16];
    }
    const float bav = P.ba[brn][0];
#pragma unroll
    for (int i = 0; i < 4; ++i) {
      float h[4], gg = 0.f;
#pragma unroll
      for (int ct = 0; ct < 4; ++ct) {
        h[ct] = fmaxf(acc[ct][i] + bcol[ct], 0.f);
        gg = fmaf(h[ct], wacol[ct], gg);
      }
#pragma unroll
      for (int o = 1; o < 16; o <<= 1) gg += __shfl_xor(gg, o);
      float alpha = 1.0f / (1.0f + __expf(-(gg + bav)));
#pragma unroll
      for (int ct = 0; ct < 4; ++ct) oacc[ct][i] = fmaf(alpha, h[ct], oacc[ct][i]);
    }
  }
#pragma unroll
  for (int ct = 0; ct < 4; ++ct)
#pragma unroll
    for (int i = 0; i < 4; ++i)
      out[(size_t)(base + kg * 4 + i) * D + ct * 16 + l16] = oacc[ct][i];
}

__global__ __launch_bounds__(256) void k_branch(
    const ushort* __restrict__ xbf, const ushort* __restrict__ axbf,
    const ushort* __restrict__ aaxbf, BranchParams P,
    const short* __restrict__ wf, float* __restrict__ out) {
  const int waveId = blockIdx.x * 4 + (threadIdx.x >> 6);
  if (waveId >= N / 16) return;
  branch_wave(xbf, axbf, aaxbf, P, wf, out, waveId * 16, threadIdx.x & 63);
}

extern "C" void kernel_launch(void* const* d_in, const int* in_sizes, int n_in,
                              void* d_out, int out_size, void* d_ws, size_t ws_size,
                              hipStream_t stream) {
  const float* x = (const float*)d_in[0];
  const int* ei = (const int*)d_in[1];
  BranchParams P;
  for (int i = 0; i < 5; ++i) {
    P.W[i] = (const float*)d_in[2 + 4 * i];
    P.b[i] = (const float*)d_in[3 + 4 * i];
    P.wa[i] = (const float*)d_in[4 + 4 * i];
    P.ba[i] = (const float*)d_in[5 + 4 * i];
  }

  // workspace: xbf 6.4M | axbf 6.4M | aaxbf 6.4M | pos 200K | srcs 6.4M | wf 40K
  char* w = (char*)d_ws;
  uint* xbf = (uint*)w;      w += (size_t)N * D * 2;
  uint* axbf = (uint*)w;     w += (size_t)N * D * 2;
  uint* aaxbf = (uint*)w;    w += (size_t)N * D * 2;
  int* pos = (int*)w;        w += (size_t)N * 4;
  ushort* srcs = (ushort*)w; w += (size_t)N * SLOTS * 2;
  short* wf = (short*)w;

  hipLaunchKernelGGL(k_zero_prep, dim3(ZB + PB + 1), dim3(256), 0, stream,
                     pos, x, xbf, P, wf);
  hipLaunchKernelGGL(k_fill8, dim3(EBLK * 8), dim3(256), 0, stream, ei, pos, srcs);
  hipLaunchKernelGGL(k_agg, dim3(N / 4), dim3(256), 0, stream, pos, srcs, xbf, axbf);
  hipLaunchKernelGGL(k_agg, dim3(N / 4), dim3(256), 0, stream, pos, srcs, axbf, aaxbf);
  hipLaunchKernelGGL(k_branch, dim3((N / 16 + 3) / 4), dim3(256), 0, stream,
                     (const ushort*)xbf, (const ushort*)axbf, (const ushort*)aaxbf,
                     P, wf, (float*)d_out);
}

// Round 14
// 111.523 us; speedup vs baseline: 1.6808x; 1.0241x over previous
//
#include <hip/hip_runtime.h>
#include <hip/hip_bf16.h>

constexpr int N = 50000;
constexpr int E = 800000;
constexpr int D = 64;
constexpr int GSZ = N / 8;        // 6250 nodes per XCD group
constexpr int SLOTS = 64;         // fixed CSR row width (max deg ~40 whp)
constexpr int ZB = 49;            // zero blocks: 12500 int4 / 256
constexpr int PB = 1563;          // prepx blocks: 400000 uint4-groups / 256
constexpr int EBLK = E / 256;     // 3125

typedef __attribute__((ext_vector_type(8))) short s8v;    // 8 bf16
typedef __attribute__((ext_vector_type(4))) float f32x4;  // mfma accumulator

struct BranchParams {
  const float* W[5];
  const float* b[5];
  const float* wa[5];
  const float* ba[5];
};

__device__ __forceinline__ short f2bf(float f) {  // RNE float->bf16 bits
  unsigned u = __float_as_uint(f);
  u += 0x7fff + ((u >> 16) & 1);
  return (short)(u >> 16);
}
__device__ __forceinline__ float bflo(unsigned v) { return __uint_as_float(v << 16); }
__device__ __forceinline__ float bfhi(unsigned v) { return __uint_as_float(v & 0xffff0000u); }
__device__ __forceinline__ float bfs(short s) {
  return __uint_as_float(((unsigned)(unsigned short)s) << 16);
}
__device__ __forceinline__ unsigned pack2(float lo, float hi) {
  return ((unsigned)(unsigned short)f2bf(lo)) |
         (((unsigned)(unsigned short)f2bf(hi)) << 16);
}

__device__ __forceinline__ void prepw_frag(const BranchParams& P,
                                           short* __restrict__ wf,
                                           int bfrag, int lane) {
  int br = bfrag >> 3, ct = (bfrag >> 1) & 3, kk = bfrag & 1;
  const float* W = P.W[br];
  int col = ct * 16 + (lane & 15);
  int k0 = kk * 32 + (lane >> 4) * 8;
  s8v v;
#pragma unroll
  for (int j = 0; j < 8; ++j) v[j] = f2bf(W[(k0 + j) * D + col]);
  ((s8v*)wf)[bfrag * 64 + lane] = v;
}

// ---- K1: zero slot-cursors (must precede fill) --------------------------
__global__ __launch_bounds__(256) void k_zero(int4* __restrict__ pos4) {
  int t = blockIdx.x * 256 + threadIdx.x;
  if (t < N / 4) pos4[t] = int4{0, 0, 0, 0};
}

// ---- K2: W-frags | x->bf16 | fixed-slot XCD-partitioned CSR fill --------
// prepx/prepw have no dependency on pos, so they overlap with the fill blocks.
__global__ __launch_bounds__(256) void k_fill_prep(
    const int* __restrict__ ei, int* __restrict__ pos,
    ushort* __restrict__ srcs, const float* __restrict__ x,
    uint* __restrict__ xbf, BranchParams P, short* __restrict__ wf) {
  int b = blockIdx.x;
  if (b == 0) {
    int wid = threadIdx.x >> 6, lane = threadIdx.x & 63;
    for (int bfrag = wid; bfrag < 40; bfrag += 4) prepw_frag(P, wf, bfrag, lane);
  } else if (b <= PB) {
    int t = (b - 1) * 256 + threadIdx.x;
    if (t < N * D / 8) {
      const float4* p = (const float4*)(x + (size_t)t * 8);
      float4 a = p[0], c = p[1];
      uint4 o;
      o.x = pack2(a.x, a.y);
      o.y = pack2(a.z, a.w);
      o.z = pack2(c.x, c.y);
      o.w = pack2(c.z, c.w);
      ((uint4*)xbf)[t] = o;
    }
  } else {
    int fb = b - 1 - PB;                 // 0 .. 8*EBLK-1
    int g = fb & 7;
    int e = (fb >> 3) * 256 + threadIdx.x;
    int dst = ei[E + e];
    if ((unsigned)(dst - g * GSZ) < (unsigned)GSZ) {
      int slot = atomicAdd(&pos[dst], 1);
      if (slot < SLOTS) srcs[dst * SLOTS + slot] = (ushort)ei[e];
    }
  }
}

// ---- K3/K4: mean aggregation (uint2 gathers: 4 edge-rows per VMEM instr,
//             16 rows in flight per wave) --------------------------------
__global__ __launch_bounds__(256) void k_agg(
    const int* __restrict__ pos, const ushort* __restrict__ srcs,
    const uint2* __restrict__ in2, uint2* __restrict__ out2) {
  int node = blockIdx.x * 4 + (threadIdx.x >> 6);
  int lane = threadIdx.x & 63;
  int eg = lane >> 4;   // edge subgroup 0..3 (4 edges per load instruction)
  int fq = lane & 15;   // feature-quad index (uint2 = 4 bf16 features)
  int deg = pos[node];
  int m = min(deg, SLOTS);
  int start = node * SLOTS;

  float a0 = 0.f, b0 = 0.f, c0 = 0.f, d0 = 0.f;
  float a1 = 0.f, b1 = 0.f, c1 = 0.f, d1 = 0.f;
  float a2 = 0.f, b2 = 0.f, c2 = 0.f, d2 = 0.f;
  float a3 = 0.f, b3 = 0.f, c3 = 0.f, d3 = 0.f;
  int i = 0;
  for (; i + 16 <= m; i += 16) {  // 16 rows in flight / 4 instructions
    int s0 = srcs[start + i + eg];
    int s1 = srcs[start + i + 4 + eg];
    int s2 = srcs[start + i + 8 + eg];
    int s3 = srcs[start + i + 12 + eg];
    uint2 v0 = in2[s0 * 16 + fq];
    uint2 v1 = in2[s1 * 16 + fq];
    uint2 v2 = in2[s2 * 16 + fq];
    uint2 v3 = in2[s3 * 16 + fq];
    a0 += bflo(v0.x); b0 += bfhi(v0.x); c0 += bflo(v0.y); d0 += bfhi(v0.y);
    a1 += bflo(v1.x); b1 += bfhi(v1.x); c1 += bflo(v1.y); d1 += bfhi(v1.y);
    a2 += bflo(v2.x); b2 += bfhi(v2.x); c2 += bflo(v2.y); d2 += bfhi(v2.y);
    a3 += bflo(v3.x); b3 += bfhi(v3.x); c3 += bflo(v3.y); d3 += bfhi(v3.y);
  }
  for (; i + 4 <= m; i += 4) {
    int s0 = srcs[start + i + eg];
    uint2 v0 = in2[s0 * 16 + fq];
    a0 += bflo(v0.x); b0 += bfhi(v0.x); c0 += bflo(v0.y); d0 += bfhi(v0.y);
  }
  int rem = m - i;
  if (eg < rem) {
    int s0 = srcs[start + i + eg];
    uint2 v0 = in2[s0 * 16 + fq];
    a0 += bflo(v0.x); b0 += bfhi(v0.x); c0 += bflo(v0.y); d0 += bfhi(v0.y);
  }
  float A = (a0 + a1) + (a2 + a3);
  float B = (b0 + b1) + (b2 + b3);
  float C = (c0 + c1) + (c2 + c3);
  float Dv = (d0 + d1) + (d2 + d3);
  A += __shfl_xor(A, 16); A += __shfl_xor(A, 32);
  B += __shfl_xor(B, 16); B += __shfl_xor(B, 32);
  C += __shfl_xor(C, 16); C += __shfl_xor(C, 32);
  Dv += __shfl_xor(Dv, 16); Dv += __shfl_xor(Dv, 32);
  if (eg == 0) {
    float inv = 1.0f / fmaxf((float)deg, 1.0f);  // true degree denominator
    uint2 o;
    o.x = pack2(A * inv, B * inv);
    o.y = pack2(C * inv, Dv * inv);
    out2[node * 16 + fq] = o;
  }
}

// ---- K5: fused 5-branch MFMA GEMM + ReLU + sigmoid gate + gated sum -----
__device__ __forceinline__ void branch_wave(
    const ushort* __restrict__ xbf, const ushort* __restrict__ axbf,
    const ushort* __restrict__ aaxbf, const BranchParams& P,
    const short* __restrict__ wf, float* __restrict__ out,
    int base, int lane) {
  const int l16 = lane & 15;
  const int kg = lane >> 4;

  const s8v* xr = (const s8v*)(xbf + (size_t)(base + l16) * D);
  const s8v* ar = (const s8v*)(axbf + (size_t)(base + l16) * D);
  const s8v* cr = (const s8v*)(aaxbf + (size_t)(base + l16) * D);
  s8v xv[2], av[2], bv[2];
  xv[0] = xr[kg]; xv[1] = xr[4 + kg];
  av[0] = ar[kg]; av[1] = ar[4 + kg];
  bv[0] = cr[kg]; bv[1] = cr[4 + kg];

  s8v hpv[2], hp2v[2];
#pragma unroll
  for (int kk = 0; kk < 2; ++kk) {
#pragma unroll
    for (int j = 0; j < 8; ++j) {
      float fx = bfs(xv[kk][j]), fa = bfs(av[kk][j]), fb = bfs(bv[kk][j]);
      hpv[kk][j] = f2bf(fx - fa);
      hp2v[kk][j] = f2bf(fx - 2.0f * fa + fb);
    }
  }

  f32x4 oacc[4] = {{0.f, 0.f, 0.f, 0.f}, {0.f, 0.f, 0.f, 0.f},
                   {0.f, 0.f, 0.f, 0.f}, {0.f, 0.f, 0.f, 0.f}};
  const s8v* wf8 = (const s8v*)wf;

#pragma unroll
  for (int brn = 0; brn < 5; ++brn) {
    s8v a0, a1;
    switch (brn) {
      case 0: a0 = hpv[0]; a1 = hpv[1]; break;
      case 1: a0 = av[0]; a1 = av[1]; break;
      case 2: a0 = xv[0]; a1 = xv[1]; break;
      case 3: a0 = hp2v[0]; a1 = hp2v[1]; break;
      default: a0 = bv[0]; a1 = bv[1]; break;
    }
    f32x4 acc[4];
#pragma unroll
    for (int ct = 0; ct < 4; ++ct) {
      f32x4 a = {0.f, 0.f, 0.f, 0.f};
      a = __builtin_amdgcn_mfma_f32_16x16x32_bf16(
          a0, wf8[((brn * 4 + ct) * 2 + 0) * 64 + lane], a, 0, 0, 0);
      a = __builtin_amdgcn_mfma_f32_16x16x32_bf16(
          a1, wf8[((brn * 4 + ct) * 2 + 1) * 64 + lane], a, 0, 0, 0);
      acc[ct] = a;
    }
    float bcol[4], wacol[4];
#pragma unroll
    for (int ct = 0; ct < 4; ++ct) {
      bcol[ct] = P.b[brn][ct * 16 + l16];
      wacol[ct] = P.wa[brn][ct * 16 + l16];
    }
    const float bav = P.ba[brn][0];
#pragma unroll
    for (int i = 0; i < 4; ++i) {
      float h[4], gg = 0.f;
#pragma unroll
      for (int ct = 0; ct < 4; ++ct) {
        h[ct] = fmaxf(acc[ct][i] + bcol[ct], 0.f);
        gg = fmaf(h[ct], wacol[ct], gg);
      }
#pragma unroll
      for (int o = 1; o < 16; o <<= 1) gg += __shfl_xor(gg, o);
      float alpha = 1.0f / (1.0f + __expf(-(gg + bav)));
#pragma unroll
      for (int ct = 0; ct < 4; ++ct) oacc[ct][i] = fmaf(alpha, h[ct], oacc[ct][i]);
    }
  }
#pragma unroll
  for (int ct = 0; ct < 4; ++ct)
#pragma unroll
    for (int i = 0; i < 4; ++i)
      out[(size_t)(base + kg * 4 + i) * D + ct * 16 + l16] = oacc[ct][i];
}

__global__ __launch_bounds__(256) void k_branch(
    const ushort* __restrict__ xbf, const ushort* __restrict__ axbf,
    const ushort* __restrict__ aaxbf, BranchParams P,
    const short* __restrict__ wf, float* __restrict__ out) {
  const int waveId = blockIdx.x * 4 + (threadIdx.x >> 6);
  if (waveId >= N / 16) return;
  branch_wave(xbf, axbf, aaxbf, P, wf, out, waveId * 16, threadIdx.x & 63);
}

extern "C" void kernel_launch(void* const* d_in, const int* in_sizes, int n_in,
                              void* d_out, int out_size, void* d_ws, size_t ws_size,
                              hipStream_t stream) {
  const float* x = (const float*)d_in[0];
  const int* ei = (const int*)d_in[1];
  BranchParams P;
  for (int i = 0; i < 5; ++i) {
    P.W[i] = (const float*)d_in[2 + 4 * i];
    P.b[i] = (const float*)d_in[3 + 4 * i];
    P.wa[i] = (const float*)d_in[4 + 4 * i];
    P.ba[i] = (const float*)d_in[5 + 4 * i];
  }

  // workspace: xbf 6.4M | axbf 6.4M | aaxbf 6.4M | pos 200K | srcs 6.4M | wf 40K
  char* w = (char*)d_ws;
  uint* xbf = (uint*)w;      w += (size_t)N * D * 2;
  uint* axbf = (uint*)w;     w += (size_t)N * D * 2;
  uint* aaxbf = (uint*)w;    w += (size_t)N * D * 2;
  int* pos = (int*)w;        w += (size_t)N * 4;
  ushort* srcs = (ushort*)w; w += (size_t)N * SLOTS * 2;
  short* wf = (short*)w;

  hipLaunchKernelGGL(k_zero, dim3(ZB), dim3(256), 0, stream, (int4*)pos);
  hipLaunchKernelGGL(k_fill_prep, dim3(1 + PB + 8 * EBLK), dim3(256), 0, stream,
                     ei, pos, srcs, x, xbf, P, wf);
  hipLaunchKernelGGL(k_agg, dim3(N / 4), dim3(256), 0, stream,
                     pos, srcs, (const uint2*)xbf, (uint2*)axbf);
  hipLaunchKernelGGL(k_agg, dim3(N / 4), dim3(256), 0, stream,
                     pos, srcs, (const uint2*)axbf, (uint2*)aaxbf);
  hipLaunchKernelGGL(k_branch, dim3((N / 16 + 3) / 4), dim3(256), 0, stream,
                     (const ushort*)xbf, (const ushort*)axbf, (const ushort*)aaxbf,
                     P, wf, (float*)d_out);
}